// Round 1
// baseline (951.289 us; speedup 1.0000x reference)
//
#include <hip/hip_runtime.h>
#include <math.h>

// Problem constants: K=30 bands, B=4, T=512, N=128, Vd=64, NKB=120
// ws layout (float offsets):
static constexpr size_t XB_OFF  = 0;          // 120*512*128 = 7,864,320  (reused as outkb)
static constexpr size_t Q_OFF   = 7864320;    // 7,864,320
static constexpr size_t KK_OFF  = 15728640;   // 7,864,320
static constexpr size_t V_OFF   = 23592960;   // 3,932,160
static constexpr size_t RS_OFF  = 27525120;   // 120*512*8 = 491,520
static constexpr size_t LAM_OFF = 28016640;   // 128
static constexpr size_t OM_OFF  = 28016768;   // 3,932,160  -> total 31,948,928 floats (~122 MB)

__global__ __launch_bounds__(256) void k_tin(const float* __restrict__ x, float* __restrict__ xb) {
    int b = blockIdx.x >> 9, t = blockIdx.x & 511;
    __shared__ float ld[3840];
    const float* xp = x + ((size_t)b * 1966080 + (size_t)t * 30);
    for (int idx = threadIdx.x; idx < 3840; idx += 256) {
        int n = idx / 30, k = idx - n * 30;
        ld[idx] = xp[(size_t)n * 15360 + k];
    }
    __syncthreads();
    for (int idx = threadIdx.x; idx < 3840; idx += 256) {
        int k = idx >> 7, n = idx & 127;
        xb[(((size_t)(k * 4 + b)) * 512 + t) * 128 + n] = ld[n * 30 + k];
    }
}

__global__ __launch_bounds__(256) void k_qkv(const float* __restrict__ xb,
        const float* __restrict__ Wq, const float* __restrict__ Wk, const float* __restrict__ Wv,
        float* __restrict__ q, float* __restrict__ kk, float* __restrict__ v) {
    int kb = blockIdx.z, band = kb >> 2;
    int t0 = blockIdx.x * 64;
    int mt = blockIdx.y;
    const float* W; float* O; int mstride;
    if (mt < 2)      { W = Wq + (size_t)band * 16384 + (size_t)mt * 8192;       O = q  + (size_t)kb * 65536 + mt * 64;       mstride = 128; }
    else if (mt < 4) { W = Wk + (size_t)band * 16384 + (size_t)(mt - 2) * 8192; O = kk + (size_t)kb * 65536 + (mt - 2) * 64; mstride = 128; }
    else             { W = Wv + (size_t)band * 8192;                            O = v  + (size_t)kb * 32768;                 mstride = 64; }
    const float* A = xb + ((size_t)kb * 512 + t0) * 128;
    __shared__ __attribute__((aligned(16))) float At[64 * 33];
    __shared__ __attribute__((aligned(16))) float Wt[64 * 33];
    int tid = threadIdx.x, ty = tid >> 4, tx = tid & 15;
    float acc[4][4] = {};
    for (int n0 = 0; n0 < 128; n0 += 32) {
#pragma unroll
        for (int it = 0; it < 2; ++it) {
            int f = tid + it * 256;
            int r = f >> 3, c4 = (f & 7) * 4;
            float4 av = *(const float4*)(A + (size_t)r * 128 + n0 + c4);
            At[r * 33 + c4 + 0] = av.x; At[r * 33 + c4 + 1] = av.y; At[r * 33 + c4 + 2] = av.z; At[r * 33 + c4 + 3] = av.w;
            float4 wv = *(const float4*)(W + (size_t)r * 128 + n0 + c4);
            Wt[r * 33 + c4 + 0] = wv.x; Wt[r * 33 + c4 + 1] = wv.y; Wt[r * 33 + c4 + 2] = wv.z; Wt[r * 33 + c4 + 3] = wv.w;
        }
        __syncthreads();
#pragma unroll
        for (int ks = 0; ks < 32; ++ks) {
            float a[4], bb[4];
#pragma unroll
            for (int i = 0; i < 4; ++i) a[i] = At[(ty * 4 + i) * 33 + ks];
#pragma unroll
            for (int j = 0; j < 4; ++j) bb[j] = Wt[(tx * 4 + j) * 33 + ks];
#pragma unroll
            for (int i = 0; i < 4; ++i)
#pragma unroll
                for (int j = 0; j < 4; ++j) acc[i][j] += a[i] * bb[j];
        }
        __syncthreads();
    }
#pragma unroll
    for (int i = 0; i < 4; ++i) {
        int t = t0 + ty * 4 + i;
#pragma unroll
        for (int j = 0; j < 4; ++j) O[(size_t)t * mstride + tx * 4 + j] = acc[i][j];
    }
}

// rows=32 per block, 128 threads: rg=tid>>4 (8 groups x 4 rows), sg=tid&15 (16 groups x 4 s)
__global__ __launch_bounds__(128) void k_stats(const float* __restrict__ q, const float* __restrict__ kk,
                                               float* __restrict__ rowst) {
    int kb = blockIdx.y;
    int t0 = blockIdx.x * 32;
    int tid = threadIdx.x;
    int rg = tid >> 4, sg = tid & 15;
    __shared__ __attribute__((aligned(16))) float qt[32 * 132];
    __shared__ __attribute__((aligned(16))) float kt[64 * 132];
    const float* qbase = q + ((size_t)kb * 512 + t0) * 128;
    for (int f = tid; f < 1024; f += 128) {
        int r = f >> 5, c4 = (f & 31) * 4;
        float4 qv = *(const float4*)(qbase + (size_t)r * 128 + c4);
        qt[r * 132 + c4 + 0] = qv.x; qt[r * 132 + c4 + 1] = qv.y; qt[r * 132 + c4 + 2] = qv.z; qt[r * 132 + c4 + 3] = qv.w;
    }
    float m1[4], l1[4], s1[4], n1[4], m2[4], l2[4], s2[4], n2[4];
#pragma unroll
    for (int r = 0; r < 4; ++r) {
        m1[r] = -1e30f; l1[r] = 0.f; s1[r] = 0.f; n1[r] = 1e30f;
        m2[r] = -1e30f; l2[r] = 0.f; s2[r] = 0.f; n2[r] = 1e30f;
    }
    const float* kbase = kk + (size_t)kb * 65536;
    for (int s0 = 0; s0 < 512; s0 += 64) {
        __syncthreads();
        for (int f = tid; f < 2048; f += 128) {
            int r = f >> 5, c4 = (f & 31) * 4;
            float4 kv = *(const float4*)(kbase + (size_t)(s0 + r) * 128 + c4);
            kt[r * 132 + c4 + 0] = kv.x; kt[r * 132 + c4 + 1] = kv.y; kt[r * 132 + c4 + 2] = kv.z; kt[r * 132 + c4 + 3] = kv.w;
        }
        __syncthreads();
        float d1[4][4] = {}, d2[4][4] = {};
#pragma unroll 2
        for (int i = 0; i < 64; i += 4) {
            float4 qa[4], ka[4];
#pragma unroll
            for (int r = 0; r < 4; ++r) qa[r] = *(const float4*)(qt + (rg * 4 + r) * 132 + i);
#pragma unroll
            for (int c = 0; c < 4; ++c) ka[c] = *(const float4*)(kt + (sg * 4 + c) * 132 + i);
#pragma unroll
            for (int r = 0; r < 4; ++r)
#pragma unroll
                for (int c = 0; c < 4; ++c)
                    d1[r][c] += qa[r].x * ka[c].x + qa[r].y * ka[c].y + qa[r].z * ka[c].z + qa[r].w * ka[c].w;
#pragma unroll
            for (int r = 0; r < 4; ++r) qa[r] = *(const float4*)(qt + (rg * 4 + r) * 132 + 64 + i);
#pragma unroll
            for (int c = 0; c < 4; ++c) ka[c] = *(const float4*)(kt + (sg * 4 + c) * 132 + 64 + i);
#pragma unroll
            for (int r = 0; r < 4; ++r)
#pragma unroll
                for (int c = 0; c < 4; ++c)
                    d2[r][c] += qa[r].x * ka[c].x + qa[r].y * ka[c].y + qa[r].z * ka[c].z + qa[r].w * ka[c].w;
        }
#pragma unroll
        for (int r = 0; r < 4; ++r)
#pragma unroll
            for (int c = 0; c < 4; ++c) {
                float lg = d1[r][c] * 0.25f;
                n1[r] = fminf(n1[r], lg);
                if (lg > m1[r]) { float sc = __expf(m1[r] - lg); l1[r] = l1[r] * sc + 1.0f; s1[r] = s1[r] * sc * sc + 1.0f; m1[r] = lg; }
                else            { float e = __expf(lg - m1[r]); l1[r] += e; s1[r] += e * e; }
                lg = d2[r][c] * 0.25f;
                n2[r] = fminf(n2[r], lg);
                if (lg > m2[r]) { float sc = __expf(m2[r] - lg); l2[r] = l2[r] * sc + 1.0f; s2[r] = s2[r] * sc * sc + 1.0f; m2[r] = lg; }
                else            { float e = __expf(lg - m2[r]); l2[r] += e; s2[r] += e * e; }
            }
    }
#pragma unroll
    for (int off = 1; off < 16; off <<= 1) {
#pragma unroll
        for (int r = 0; r < 4; ++r) {
            float mo = __shfl_xor(m1[r], off), lo = __shfl_xor(l1[r], off), so = __shfl_xor(s1[r], off), no = __shfl_xor(n1[r], off);
            float mN = fmaxf(m1[r], mo), ea = __expf(m1[r] - mN), eb = __expf(mo - mN);
            l1[r] = l1[r] * ea + lo * eb; s1[r] = s1[r] * ea * ea + so * eb * eb; m1[r] = mN; n1[r] = fminf(n1[r], no);
            mo = __shfl_xor(m2[r], off); lo = __shfl_xor(l2[r], off); so = __shfl_xor(s2[r], off); no = __shfl_xor(n2[r], off);
            mN = fmaxf(m2[r], mo); ea = __expf(m2[r] - mN); eb = __expf(mo - mN);
            l2[r] = l2[r] * ea + lo * eb; s2[r] = s2[r] * ea * ea + so * eb * eb; m2[r] = mN; n2[r] = fminf(n2[r], no);
        }
    }
    if (sg == 0) {
#pragma unroll
        for (int r = 0; r < 4; ++r) {
            float* rp = rowst + ((size_t)kb * 512 + t0 + rg * 4 + r) * 8;
            rp[0] = m1[r]; rp[1] = l1[r]; rp[2] = s1[r] / (l1[r] * l1[r]); rp[3] = __expf(n1[r] - m1[r]) / l1[r];
            rp[4] = m2[r]; rp[5] = l2[r]; rp[6] = s2[r] / (l2[r] * l2[r]); rp[7] = __expf(n2[r] - m2[r]) / l2[r];
        }
    }
}

__global__ __launch_bounds__(256) void k_lam(const float* __restrict__ rowst,
        const float* __restrict__ W1, const float* __restrict__ b1,
        const float* __restrict__ W2, const float* __restrict__ b2, float* __restrict__ lam) {
    int kb = blockIdx.x, band = kb >> 2;
    int tid = threadIdx.x;
    float ss1 = 0.f, mx1 = -1e30f, mn1 = 1e30f, ss2 = 0.f, mx2 = -1e30f, mn2 = 1e30f;
    for (int t = tid; t < 512; t += 256) {
        const float* r = rowst + ((size_t)kb * 512 + t) * 8;
        ss1 += r[2]; mx1 = fmaxf(mx1, 1.0f / r[1]); mn1 = fminf(mn1, r[3]);
        ss2 += r[6]; mx2 = fmaxf(mx2, 1.0f / r[5]); mn2 = fminf(mn2, r[7]);
    }
    __shared__ float red[256 * 6];
    red[tid] = ss1; red[256 + tid] = mx1; red[512 + tid] = mn1;
    red[768 + tid] = ss2; red[1024 + tid] = mx2; red[1280 + tid] = mn2;
    __syncthreads();
    for (int h = 128; h > 0; h >>= 1) {
        if (tid < h) {
            red[tid] += red[tid + h];
            red[256 + tid] = fmaxf(red[256 + tid], red[256 + tid + h]);
            red[512 + tid] = fminf(red[512 + tid], red[512 + tid + h]);
            red[768 + tid] += red[768 + tid + h];
            red[1024 + tid] = fmaxf(red[1024 + tid], red[1024 + tid + h]);
            red[1280 + tid] = fminf(red[1280 + tid], red[1280 + tid + h]);
        }
        __syncthreads();
    }
    if (tid == 0) {
        float stats[8];
        stats[0] = 1.0f / 512.0f;
        stats[1] = sqrtf(fmaxf(red[0] - 1.0f, 0.0f) / 262143.0f);
        stats[2] = red[256]; stats[3] = red[512];
        stats[4] = 1.0f / 512.0f;
        stats[5] = sqrtf(fmaxf(red[768] - 1.0f, 0.0f) / 262143.0f);
        stats[6] = red[1024]; stats[7] = red[1280];
        float z = b2[band];
        for (int hh = 0; hh < 16; ++hh) {
            float a = b1[band * 16 + hh];
            for (int i = 0; i < 8; ++i) a += stats[i] * W1[band * 128 + hh * 8 + i];
            z += fmaxf(a, 0.0f) * W2[band * 16 + hh];
        }
        lam[kb] = 1.0f / (1.0f + __expf(-z));
    }
}

// rows=32, s-chunk=64, 128 threads; logits reg-blocked 4x4, then p-tile in LDS, then p@v
__global__ __launch_bounds__(128) void k_pv(const float* __restrict__ q, const float* __restrict__ kk,
        const float* __restrict__ v, const float* __restrict__ rowst, const float* __restrict__ lamv,
        float* __restrict__ omid) {
    int kb = blockIdx.y;
    int t0 = blockIdx.x * 32;
    int tid = threadIdx.x;
    int rg = tid >> 4, sg = tid & 15;
    __shared__ __attribute__((aligned(16))) float qt[32 * 132];
    __shared__ __attribute__((aligned(16))) float kt[64 * 36];
    __shared__ __attribute__((aligned(16))) float vt[64 * 64];
    __shared__ __attribute__((aligned(16))) float pt[32 * 76];
    const float* qbase = q + ((size_t)kb * 512 + t0) * 128;
    for (int f = tid; f < 1024; f += 128) {
        int r = f >> 5, c4 = (f & 31) * 4;
        float4 qv = *(const float4*)(qbase + (size_t)r * 128 + c4);
        qt[r * 132 + c4 + 0] = qv.x; qt[r * 132 + c4 + 1] = qv.y; qt[r * 132 + c4 + 2] = qv.z; qt[r * 132 + c4 + 3] = qv.w;
    }
    float mm1[4], il1[4], mm2[4], il2[4];
#pragma unroll
    for (int r = 0; r < 4; ++r) {
        const float* rp = rowst + ((size_t)kb * 512 + t0 + rg * 4 + r) * 8;
        mm1[r] = rp[0]; il1[r] = 1.0f / rp[1]; mm2[r] = rp[4]; il2[r] = 1.0f / rp[5];
    }
    float lam = lamv[kb];
    float acc[4][4] = {};
    const float* kbase = kk + (size_t)kb * 65536;
    const float* vbase = v + (size_t)kb * 32768;
    for (int s0 = 0; s0 < 512; s0 += 64) {
        __syncthreads();
        for (int f = tid; f < 1024; f += 128) {
            int r = f >> 4, c4 = (f & 15) * 4;
            *(float4*)(vt + r * 64 + c4) = *(const float4*)(vbase + (size_t)(s0 + r) * 64 + c4);
        }
        float d1[4][4] = {}, d2[4][4] = {};
#pragma unroll
        for (int ic = 0; ic < 4; ++ic) {
            __syncthreads();
            for (int f = tid; f < 512; f += 128) {
                int r = f >> 3, c4 = (f & 7) * 4;
                *(float4*)(kt + r * 36 + c4) = *(const float4*)(kbase + (size_t)(s0 + r) * 128 + ic * 32 + c4);
            }
            __syncthreads();
            int qoff = ic * 32;
#pragma unroll 2
            for (int i = 0; i < 32; i += 4) {
                float4 qa[4], ka[4];
#pragma unroll
                for (int r = 0; r < 4; ++r) qa[r] = *(const float4*)(qt + (rg * 4 + r) * 132 + qoff + i);
#pragma unroll
                for (int c = 0; c < 4; ++c) ka[c] = *(const float4*)(kt + (sg * 4 + c) * 36 + i);
                if (ic < 2) {
#pragma unroll
                    for (int r = 0; r < 4; ++r)
#pragma unroll
                        for (int c = 0; c < 4; ++c)
                            d1[r][c] += qa[r].x * ka[c].x + qa[r].y * ka[c].y + qa[r].z * ka[c].z + qa[r].w * ka[c].w;
                } else {
#pragma unroll
                    for (int r = 0; r < 4; ++r)
#pragma unroll
                        for (int c = 0; c < 4; ++c)
                            d2[r][c] += qa[r].x * ka[c].x + qa[r].y * ka[c].y + qa[r].z * ka[c].z + qa[r].w * ka[c].w;
                }
            }
        }
#pragma unroll
        for (int r = 0; r < 4; ++r) {
            float tmp[4];
#pragma unroll
            for (int c = 0; c < 4; ++c) {
                float e1 = __expf(d1[r][c] * 0.25f - mm1[r]) * il1[r];
                float e2 = __expf(d2[r][c] * 0.25f - mm2[r]) * il2[r];
                tmp[c] = e1 - lam * e2;
            }
            *(float4*)(pt + (rg * 4 + r) * 76 + sg * 4) = make_float4(tmp[0], tmp[1], tmp[2], tmp[3]);
        }
        __syncthreads();
#pragma unroll 4
        for (int sl4 = 0; sl4 < 64; sl4 += 4) {
            float pl[4][4];
#pragma unroll
            for (int r = 0; r < 4; ++r) {
                float4 pr = *(const float4*)(pt + (rg * 4 + r) * 76 + sl4);
                pl[r][0] = pr.x; pl[r][1] = pr.y; pl[r][2] = pr.z; pl[r][3] = pr.w;
            }
#pragma unroll
            for (int u = 0; u < 4; ++u) {
                float4 vv = *(const float4*)(vt + (sl4 + u) * 64 + sg * 4);
#pragma unroll
                for (int r = 0; r < 4; ++r) {
                    acc[r][0] += pl[r][u] * vv.x;
                    acc[r][1] += pl[r][u] * vv.y;
                    acc[r][2] += pl[r][u] * vv.z;
                    acc[r][3] += pl[r][u] * vv.w;
                }
            }
        }
    }
#pragma unroll
    for (int r = 0; r < 4; ++r) {
        float* op = omid + ((size_t)kb * 512 + t0 + rg * 4 + r) * 64 + sg * 4;
        *(float4*)op = make_float4(acc[r][0], acc[r][1], acc[r][2], acc[r][3]);
    }
}

__global__ __launch_bounds__(256) void k_wo(const float* __restrict__ omid, const float* __restrict__ Wo,
                                            const float* __restrict__ bo, float* __restrict__ outkb) {
    int kb = blockIdx.z, band = kb >> 2;
    int t0 = blockIdx.x * 64;
    int m0 = blockIdx.y * 64;
    const float* A = omid + ((size_t)kb * 512 + t0) * 64;
    const float* W = Wo + (size_t)band * 8192 + (size_t)m0 * 64;
    __shared__ __attribute__((aligned(16))) float At[64 * 33];
    __shared__ __attribute__((aligned(16))) float Wt[64 * 33];
    int tid = threadIdx.x, ty = tid >> 4, tx = tid & 15;
    float acc[4][4] = {};
    for (int n0 = 0; n0 < 64; n0 += 32) {
#pragma unroll
        for (int it = 0; it < 2; ++it) {
            int f = tid + it * 256;
            int r = f >> 3, c4 = (f & 7) * 4;
            float4 av = *(const float4*)(A + (size_t)r * 64 + n0 + c4);
            At[r * 33 + c4 + 0] = av.x; At[r * 33 + c4 + 1] = av.y; At[r * 33 + c4 + 2] = av.z; At[r * 33 + c4 + 3] = av.w;
            float4 wv = *(const float4*)(W + (size_t)r * 64 + n0 + c4);
            Wt[r * 33 + c4 + 0] = wv.x; Wt[r * 33 + c4 + 1] = wv.y; Wt[r * 33 + c4 + 2] = wv.z; Wt[r * 33 + c4 + 3] = wv.w;
        }
        __syncthreads();
#pragma unroll
        for (int ks = 0; ks < 32; ++ks) {
            float a[4], bb[4];
#pragma unroll
            for (int i = 0; i < 4; ++i) a[i] = At[(ty * 4 + i) * 33 + ks];
#pragma unroll
            for (int j = 0; j < 4; ++j) bb[j] = Wt[(tx * 4 + j) * 33 + ks];
#pragma unroll
            for (int i = 0; i < 4; ++i)
#pragma unroll
                for (int j = 0; j < 4; ++j) acc[i][j] += a[i] * bb[j];
        }
        __syncthreads();
    }
#pragma unroll
    for (int i = 0; i < 4; ++i) {
        int t = t0 + ty * 4 + i;
#pragma unroll
        for (int j = 0; j < 4; ++j)
            outkb[((size_t)kb * 512 + t) * 128 + m0 + tx * 4 + j] = acc[i][j] + bo[band * 128 + m0 + tx * 4 + j];
    }
}

__global__ __launch_bounds__(256) void k_tout(const float* __restrict__ outkb, float* __restrict__ out) {
    int b = blockIdx.x >> 9, t = blockIdx.x & 511;
    __shared__ float ld[30 * 129];
    for (int idx = threadIdx.x; idx < 3840; idx += 256) {
        int k = idx >> 7, n = idx & 127;
        ld[k * 129 + n] = outkb[(((size_t)(k * 4 + b)) * 512 + t) * 128 + n];
    }
    __syncthreads();
    float* op = out + ((size_t)b * 1966080 + (size_t)t * 30);
    for (int idx = threadIdx.x; idx < 3840; idx += 256) {
        int n = idx / 30, k = idx - n * 30;
        op[(size_t)n * 15360 + k] = ld[k * 129 + n];
    }
}

extern "C" void kernel_launch(void* const* d_in, const int* in_sizes, int n_in,
                              void* d_out, int out_size, void* d_ws, size_t ws_size,
                              hipStream_t stream) {
    (void)in_sizes; (void)n_in; (void)out_size; (void)ws_size;
    const float* x  = (const float*)d_in[0];
    const float* Wq = (const float*)d_in[1];
    const float* Wk = (const float*)d_in[2];
    const float* Wv = (const float*)d_in[3];
    const float* Wo = (const float*)d_in[4];
    const float* bo = (const float*)d_in[5];
    const float* W1 = (const float*)d_in[6];
    const float* b1 = (const float*)d_in[7];
    const float* W2 = (const float*)d_in[8];
    const float* b2 = (const float*)d_in[9];
    float* out = (float*)d_out;
    float* ws  = (float*)d_ws;

    float* xb    = ws + XB_OFF;
    float* q     = ws + Q_OFF;
    float* kkp   = ws + KK_OFF;
    float* vp    = ws + V_OFF;
    float* rowst = ws + RS_OFF;
    float* lam   = ws + LAM_OFF;
    float* omid  = ws + OM_OFF;
    float* outkb = xb;  // xb dead after k_qkv

    k_tin <<<2048, 256, 0, stream>>>(x, xb);
    k_qkv <<<dim3(8, 5, 120), 256, 0, stream>>>(xb, Wq, Wk, Wv, q, kkp, vp);
    k_stats<<<dim3(16, 120), 128, 0, stream>>>(q, kkp, rowst);
    k_lam <<<120, 256, 0, stream>>>(rowst, W1, b1, W2, b2, lam);
    k_pv  <<<dim3(16, 120), 128, 0, stream>>>(q, kkp, vp, rowst, lam, omid);
    k_wo  <<<dim3(8, 2, 120), 256, 0, stream>>>(omid, Wo, bo, outkb);
    k_tout<<<2048, 256, 0, stream>>>(outkb, out);
}

// Round 2
// 340.960 us; speedup vs baseline: 2.7900x; 2.7900x over previous
//
#include <hip/hip_runtime.h>
#include <math.h>

// K=30 bands, B=4, T=512, N=128, Vd=64, NKB=120
typedef __attribute__((ext_vector_type(8))) short bf16x8;
typedef __attribute__((ext_vector_type(4))) float f32x4;

#define MFMA(a, b, c) __builtin_amdgcn_mfma_f32_16x16x32_bf16((a), (b), (c), 0, 0, 0)

__device__ inline unsigned short f2b(float f) {
    unsigned u = __builtin_bit_cast(unsigned, f);
    u += 0x7FFF + ((u >> 16) & 1);
    return (unsigned short)(u >> 16);
}

// ws byte offsets
static constexpr size_t OFF_XB    = 0;           // bf16 120*512*128
static constexpr size_t OFF_Q     = 15728640;    // bf16 120*512*128
static constexpr size_t OFF_K     = 31457280;    // bf16 120*512*128
static constexpr size_t OFF_VT    = 47185920;    // bf16 120*64*512
static constexpr size_t OFF_OM    = 55050240;    // bf16 120*512*64
static constexpr size_t OFF_WQ    = 62914560;    // bf16 30*128*128
static constexpr size_t OFF_WK    = 63897600;    // bf16 30*128*128
static constexpr size_t OFF_WV    = 64880640;    // bf16 30*64*128
static constexpr size_t OFF_WO    = 65372160;    // bf16 30*128*64
static constexpr size_t OFF_RS    = 65863680;    // f32 120*512*8
static constexpr size_t OFF_LAM   = 67829760;    // f32 120
static constexpr size_t OFF_OUTKB = 67830272;    // f32 120*512*128

__global__ __launch_bounds__(256) void k_tin(const float* __restrict__ x, unsigned short* __restrict__ xb) {
    int b = blockIdx.x >> 9, t = blockIdx.x & 511;
    __shared__ float ld[3840];
    const float* xp = x + ((size_t)b * 1966080 + (size_t)t * 30);
    for (int idx = threadIdx.x; idx < 3840; idx += 256) {
        int n = idx / 30, k = idx - n * 30;
        ld[idx] = xp[(size_t)n * 15360 + k];
    }
    __syncthreads();
    for (int idx = threadIdx.x; idx < 3840; idx += 256) {
        int k = idx >> 7, n = idx & 127;
        xb[(((size_t)(k * 4 + b)) * 512 + t) * 128 + n] = f2b(ld[n * 30 + k]);
    }
}

__global__ __launch_bounds__(256) void k_wcast(const float* __restrict__ Wq, const float* __restrict__ Wk,
        const float* __restrict__ Wv, const float* __restrict__ Wo,
        unsigned short* __restrict__ wq, unsigned short* __restrict__ wk,
        unsigned short* __restrict__ wv, unsigned short* __restrict__ wo) {
    int idx = blockIdx.x * 256 + threadIdx.x;
    if (idx < 491520)       wq[idx] = f2b(Wq[idx]);
    else if (idx < 983040)  wk[idx - 491520] = f2b(Wk[idx - 491520]);
    else if (idx < 1228800) wv[idx - 983040] = f2b(Wv[idx - 983040]);
    else if (idx < 1474560) wo[idx - 1228800] = f2b(Wo[idx - 1228800]);
}

// q,k: [kb][t][128] bf16; v stored transposed vT: [kb][vd=64][t=512] bf16
__global__ __launch_bounds__(256) void k_qkv(const unsigned short* __restrict__ xb,
        const unsigned short* __restrict__ wq, const unsigned short* __restrict__ wk,
        const unsigned short* __restrict__ wv,
        unsigned short* __restrict__ qb, unsigned short* __restrict__ kb_, unsigned short* __restrict__ vT) {
    int kb = blockIdx.y, band = kb >> 2;
    int tid = threadIdx.x, lane = tid & 63;
    int t0 = blockIdx.x * 64 + (tid >> 6) * 16;
    int rA = lane & 15, kq = (lane >> 4) * 8;
    const unsigned short* ap = xb + ((size_t)kb * 512 + t0 + rA) * 128 + kq;
    bf16x8 a0 = *(const bf16x8*)(ap);
    bf16x8 a1 = *(const bf16x8*)(ap + 32);
    bf16x8 a2 = *(const bf16x8*)(ap + 64);
    bf16x8 a3 = *(const bf16x8*)(ap + 96);
    f32x4 zero = {};
    // q then k (8 m-tiles each)
    for (int sel = 0; sel < 2; ++sel) {
        const unsigned short* W = (sel ? wk : wq) + (size_t)band * 16384;
        unsigned short* O = (sel ? kb_ : qb);
#pragma unroll
        for (int mt = 0; mt < 8; ++mt) {
            int m0 = mt * 16;
            const unsigned short* bp = W + (size_t)(m0 + rA) * 128 + kq;
            bf16x8 b0 = *(const bf16x8*)(bp);
            bf16x8 b1 = *(const bf16x8*)(bp + 32);
            bf16x8 b2 = *(const bf16x8*)(bp + 64);
            bf16x8 b3 = *(const bf16x8*)(bp + 96);
            f32x4 c = zero;
            c = MFMA(a0, b0, c); c = MFMA(a1, b1, c); c = MFMA(a2, b2, c); c = MFMA(a3, b3, c);
#pragma unroll
            for (int r = 0; r < 4; ++r) {
                int t = t0 + (lane >> 4) * 4 + r;
                O[((size_t)kb * 512 + t) * 128 + m0 + rA] = f2b(c[r]);
            }
        }
    }
    // v: 4 m-tiles, store transposed
#pragma unroll
    for (int mt = 0; mt < 4; ++mt) {
        int m0 = mt * 16;
        const unsigned short* bp = wv + (size_t)band * 8192 + (size_t)(m0 + rA) * 128 + kq;
        bf16x8 b0 = *(const bf16x8*)(bp);
        bf16x8 b1 = *(const bf16x8*)(bp + 32);
        bf16x8 b2 = *(const bf16x8*)(bp + 64);
        bf16x8 b3 = *(const bf16x8*)(bp + 96);
        f32x4 c = zero;
        c = MFMA(a0, b0, c); c = MFMA(a1, b1, c); c = MFMA(a2, b2, c); c = MFMA(a3, b3, c);
#pragma unroll
        for (int r = 0; r < 4; ++r) {
            int t = t0 + (lane >> 4) * 4 + r;
            vT[((size_t)kb * 64 + m0 + rA) * 512 + t] = f2b(c[r]);
        }
    }
}

// raw (no max-subtraction) row stats: sum e^lg, sum e^2lg, max lg, min lg  (both maps)
__global__ __launch_bounds__(256) void k_stats(const unsigned short* __restrict__ qb,
        const unsigned short* __restrict__ kb_, float* __restrict__ rowst) {
    int kb = blockIdx.y;
    int tid = threadIdx.x, lane = tid & 63;
    int t0 = blockIdx.x * 64 + (tid >> 6) * 16;
    int rA = lane & 15, kq = (lane >> 4) * 8;
    const unsigned short* qp = qb + ((size_t)kb * 512 + t0 + rA) * 128 + kq;
    bf16x8 qa0 = *(const bf16x8*)(qp);
    bf16x8 qa1 = *(const bf16x8*)(qp + 32);
    bf16x8 qa2 = *(const bf16x8*)(qp + 64);
    bf16x8 qa3 = *(const bf16x8*)(qp + 96);
    f32x4 zero = {};
    float sum1[4] = {}, ssq1[4] = {}, mx1[4], mn1[4];
    float sum2[4] = {}, ssq2[4] = {}, mx2[4], mn2[4];
#pragma unroll
    for (int r = 0; r < 4; ++r) { mx1[r] = -1e30f; mn1[r] = 1e30f; mx2[r] = -1e30f; mn2[r] = 1e30f; }
    const unsigned short* kbase = kb_ + (size_t)kb * 65536;
    for (int s0 = 0; s0 < 512; s0 += 16) {
        const unsigned short* kp = kbase + (size_t)(s0 + rA) * 128 + kq;
        bf16x8 k0 = *(const bf16x8*)(kp);
        bf16x8 k1 = *(const bf16x8*)(kp + 32);
        bf16x8 k2 = *(const bf16x8*)(kp + 64);
        bf16x8 k3 = *(const bf16x8*)(kp + 96);
        f32x4 c1 = MFMA(qa1, k1, MFMA(qa0, k0, zero));
        f32x4 c2 = MFMA(qa3, k3, MFMA(qa2, k2, zero));
#pragma unroll
        for (int r = 0; r < 4; ++r) {
            float lg = c1[r] * 0.25f;
            float e = __expf(lg);
            sum1[r] += e; ssq1[r] = fmaf(e, e, ssq1[r]);
            mx1[r] = fmaxf(mx1[r], lg); mn1[r] = fminf(mn1[r], lg);
            lg = c2[r] * 0.25f;
            e = __expf(lg);
            sum2[r] += e; ssq2[r] = fmaf(e, e, ssq2[r]);
            mx2[r] = fmaxf(mx2[r], lg); mn2[r] = fminf(mn2[r], lg);
        }
    }
#pragma unroll
    for (int off = 1; off < 16; off <<= 1) {
#pragma unroll
        for (int r = 0; r < 4; ++r) {
            sum1[r] += __shfl_xor(sum1[r], off); ssq1[r] += __shfl_xor(ssq1[r], off);
            mx1[r] = fmaxf(mx1[r], __shfl_xor(mx1[r], off)); mn1[r] = fminf(mn1[r], __shfl_xor(mn1[r], off));
            sum2[r] += __shfl_xor(sum2[r], off); ssq2[r] += __shfl_xor(ssq2[r], off);
            mx2[r] = fmaxf(mx2[r], __shfl_xor(mx2[r], off)); mn2[r] = fminf(mn2[r], __shfl_xor(mn2[r], off));
        }
    }
    if ((lane & 15) == 0) {
#pragma unroll
        for (int r = 0; r < 4; ++r) {
            float* rp = rowst + ((size_t)kb * 512 + t0 + (lane >> 4) * 4 + r) * 8;
            rp[0] = sum1[r]; rp[1] = ssq1[r]; rp[2] = mx1[r]; rp[3] = mn1[r];
            rp[4] = sum2[r]; rp[5] = ssq2[r]; rp[6] = mx2[r]; rp[7] = mn2[r];
        }
    }
}

__global__ __launch_bounds__(256) void k_lam(const float* __restrict__ rowst,
        const float* __restrict__ W1, const float* __restrict__ b1,
        const float* __restrict__ W2, const float* __restrict__ b2, float* __restrict__ lam) {
    int kb = blockIdx.x, band = kb >> 2;
    int tid = threadIdx.x;
    float ss1 = 0.f, mx1 = -1e30f, mn1 = 1e30f, ss2 = 0.f, mx2 = -1e30f, mn2 = 1e30f;
    for (int t = tid; t < 512; t += 256) {
        const float* r = rowst + ((size_t)kb * 512 + t) * 8;
        float is1 = 1.0f / r[0], is2 = 1.0f / r[4];
        ss1 += r[1] * is1 * is1;
        mx1 = fmaxf(mx1, __expf(r[2]) * is1); mn1 = fminf(mn1, __expf(r[3]) * is1);
        ss2 += r[5] * is2 * is2;
        mx2 = fmaxf(mx2, __expf(r[6]) * is2); mn2 = fminf(mn2, __expf(r[7]) * is2);
    }
    __shared__ float red[256 * 6];
    red[tid] = ss1; red[256 + tid] = mx1; red[512 + tid] = mn1;
    red[768 + tid] = ss2; red[1024 + tid] = mx2; red[1280 + tid] = mn2;
    __syncthreads();
    for (int h = 128; h > 0; h >>= 1) {
        if (tid < h) {
            red[tid] += red[tid + h];
            red[256 + tid] = fmaxf(red[256 + tid], red[256 + tid + h]);
            red[512 + tid] = fminf(red[512 + tid], red[512 + tid + h]);
            red[768 + tid] += red[768 + tid + h];
            red[1024 + tid] = fmaxf(red[1024 + tid], red[1024 + tid + h]);
            red[1280 + tid] = fminf(red[1280 + tid], red[1280 + tid + h]);
        }
        __syncthreads();
    }
    if (tid == 0) {
        float stats[8];
        stats[0] = 1.0f / 512.0f;
        stats[1] = sqrtf(fmaxf(red[0] - 1.0f, 0.0f) / 262143.0f);
        stats[2] = red[256]; stats[3] = red[512];
        stats[4] = 1.0f / 512.0f;
        stats[5] = sqrtf(fmaxf(red[768] - 1.0f, 0.0f) / 262143.0f);
        stats[6] = red[1024]; stats[7] = red[1280];
        float z = b2[band];
        for (int hh = 0; hh < 16; ++hh) {
            float a = b1[band * 16 + hh];
            for (int i = 0; i < 8; ++i) a += stats[i] * W1[band * 128 + hh * 8 + i];
            z += fmaxf(a, 0.0f) * W2[band * 16 + hh];
        }
        lam[kb] = 1.0f / (1.0f + __expf(-z));
    }
}

// recompute logits via MFMA, p = e1/l1 - lam*e2/l2 -> bf16 LDS -> PV MFMA; omid bf16 [kb][t][64]
__global__ __launch_bounds__(256) void k_pv(const unsigned short* __restrict__ qb,
        const unsigned short* __restrict__ kb_, const unsigned short* __restrict__ vT,
        const float* __restrict__ rowst, const float* __restrict__ lamv,
        unsigned short* __restrict__ omid) {
    int kb = blockIdx.y;
    int tid = threadIdx.x, lane = tid & 63, w = tid >> 6;
    int t0 = blockIdx.x * 64 + w * 16;
    int rA = lane & 15, kq = (lane >> 4) * 8;
    __shared__ unsigned short plds[4][2][16 * 40];  // [wave][dbuf][row][40]
    const unsigned short* qp = qb + ((size_t)kb * 512 + t0 + rA) * 128 + kq;
    bf16x8 qa0 = *(const bf16x8*)(qp);
    bf16x8 qa1 = *(const bf16x8*)(qp + 32);
    bf16x8 qa2 = *(const bf16x8*)(qp + 64);
    bf16x8 qa3 = *(const bf16x8*)(qp + 96);
    float il1[4], il2[4];
#pragma unroll
    for (int r = 0; r < 4; ++r) {
        const float* rp = rowst + ((size_t)kb * 512 + t0 + (lane >> 4) * 4 + r) * 8;
        il1[r] = 1.0f / rp[0]; il2[r] = 1.0f / rp[4];
    }
    float lam = lamv[kb];
    f32x4 zero = {};
    f32x4 acc[4] = {zero, zero, zero, zero};
    const unsigned short* kbase = kb_ + (size_t)kb * 65536;
    const unsigned short* vbase = vT + (size_t)kb * 32768;
    for (int s0 = 0; s0 < 512; s0 += 32) {
        int db = (s0 >> 5) & 1;
#pragma unroll
        for (int h = 0; h < 2; ++h) {
            int sc = s0 + h * 16;
            const unsigned short* kp = kbase + (size_t)(sc + rA) * 128 + kq;
            bf16x8 k0 = *(const bf16x8*)(kp);
            bf16x8 k1 = *(const bf16x8*)(kp + 32);
            bf16x8 k2 = *(const bf16x8*)(kp + 64);
            bf16x8 k3 = *(const bf16x8*)(kp + 96);
            f32x4 c1 = MFMA(qa1, k1, MFMA(qa0, k0, zero));
            f32x4 c2 = MFMA(qa3, k3, MFMA(qa2, k2, zero));
#pragma unroll
            for (int r = 0; r < 4; ++r) {
                float e1 = __expf(c1[r] * 0.25f) * il1[r];
                float e2 = __expf(c2[r] * 0.25f) * il2[r];
                plds[w][db][((lane >> 4) * 4 + r) * 40 + h * 16 + rA] = f2b(e1 - lam * e2);
            }
        }
        asm volatile("s_waitcnt lgkmcnt(0)" ::: "memory");
        __builtin_amdgcn_sched_barrier(0);
        bf16x8 pa = *(const bf16x8*)(&plds[w][db][rA * 40 + kq]);
#pragma unroll
        for (int vt = 0; vt < 4; ++vt) {
            bf16x8 vf = *(const bf16x8*)(vbase + (size_t)(vt * 16 + rA) * 512 + s0 + kq);
            acc[vt] = MFMA(pa, vf, acc[vt]);
        }
    }
#pragma unroll
    for (int vt = 0; vt < 4; ++vt)
#pragma unroll
        for (int r = 0; r < 4; ++r) {
            int t = t0 + (lane >> 4) * 4 + r;
            omid[((size_t)kb * 512 + t) * 64 + vt * 16 + rA] = f2b(acc[vt][r]);
        }
}

__global__ __launch_bounds__(256) void k_wo(const unsigned short* __restrict__ omid,
        const unsigned short* __restrict__ wo, const float* __restrict__ bo,
        float* __restrict__ outkb) {
    int kb = blockIdx.y, band = kb >> 2;
    int tid = threadIdx.x, lane = tid & 63;
    int t0 = blockIdx.x * 64 + (tid >> 6) * 16;
    int rA = lane & 15, kq = (lane >> 4) * 8;
    const unsigned short* ap = omid + ((size_t)kb * 512 + t0 + rA) * 64 + kq;
    bf16x8 a0 = *(const bf16x8*)(ap);
    bf16x8 a1 = *(const bf16x8*)(ap + 32);
    f32x4 zero = {};
#pragma unroll
    for (int mt = 0; mt < 8; ++mt) {
        int m0 = mt * 16;
        const unsigned short* bp = wo + (size_t)band * 8192 + (size_t)(m0 + rA) * 64 + kq;
        bf16x8 b0 = *(const bf16x8*)(bp);
        bf16x8 b1 = *(const bf16x8*)(bp + 32);
        f32x4 c = MFMA(a1, b1, MFMA(a0, b0, zero));
        float bias = bo[band * 128 + m0 + rA];
#pragma unroll
        for (int r = 0; r < 4; ++r) {
            int t = t0 + (lane >> 4) * 4 + r;
            outkb[((size_t)kb * 512 + t) * 128 + m0 + rA] = c[r] + bias;
        }
    }
}

__global__ __launch_bounds__(256) void k_tout(const float* __restrict__ outkb, float* __restrict__ out) {
    int b = blockIdx.x >> 9, t = blockIdx.x & 511;
    __shared__ float ld[30 * 129];
    for (int idx = threadIdx.x; idx < 3840; idx += 256) {
        int k = idx >> 7, n = idx & 127;
        ld[k * 129 + n] = outkb[(((size_t)(k * 4 + b)) * 512 + t) * 128 + n];
    }
    __syncthreads();
    float* op = out + ((size_t)b * 1966080 + (size_t)t * 30);
    for (int idx = threadIdx.x; idx < 3840; idx += 256) {
        int n = idx / 30, k = idx - n * 30;
        op[(size_t)n * 15360 + k] = ld[k * 129 + n];
    }
}

extern "C" void kernel_launch(void* const* d_in, const int* in_sizes, int n_in,
                              void* d_out, int out_size, void* d_ws, size_t ws_size,
                              hipStream_t stream) {
    (void)in_sizes; (void)n_in; (void)out_size; (void)ws_size;
    const float* x  = (const float*)d_in[0];
    const float* Wq = (const float*)d_in[1];
    const float* Wk = (const float*)d_in[2];
    const float* Wv = (const float*)d_in[3];
    const float* Wo = (const float*)d_in[4];
    const float* bo = (const float*)d_in[5];
    const float* W1 = (const float*)d_in[6];
    const float* b1 = (const float*)d_in[7];
    const float* W2 = (const float*)d_in[8];
    const float* b2 = (const float*)d_in[9];
    float* out = (float*)d_out;
    char* ws = (char*)d_ws;

    unsigned short* xb  = (unsigned short*)(ws + OFF_XB);
    unsigned short* qb  = (unsigned short*)(ws + OFF_Q);
    unsigned short* kbb = (unsigned short*)(ws + OFF_K);
    unsigned short* vT  = (unsigned short*)(ws + OFF_VT);
    unsigned short* om  = (unsigned short*)(ws + OFF_OM);
    unsigned short* wqb = (unsigned short*)(ws + OFF_WQ);
    unsigned short* wkb = (unsigned short*)(ws + OFF_WK);
    unsigned short* wvb = (unsigned short*)(ws + OFF_WV);
    unsigned short* wob = (unsigned short*)(ws + OFF_WO);
    float* rowst = (float*)(ws + OFF_RS);
    float* lam   = (float*)(ws + OFF_LAM);
    float* outkb = (float*)(ws + OFF_OUTKB);

    k_tin  <<<2048, 256, 0, stream>>>(x, xb);
    k_wcast<<<5760, 256, 0, stream>>>(Wq, Wk, Wv, Wo, wqb, wkb, wvb, wob);
    k_qkv  <<<dim3(8, 120), 256, 0, stream>>>(xb, wqb, wkb, wvb, qb, kbb, vT);
    k_stats<<<dim3(8, 120), 256, 0, stream>>>(qb, kbb, rowst);
    k_lam  <<<120, 256, 0, stream>>>(rowst, W1, b1, W2, b2, lam);
    k_pv   <<<dim3(8, 120), 256, 0, stream>>>(qb, kbb, vT, rowst, lam, om);
    k_wo   <<<dim3(8, 120), 256, 0, stream>>>(om, wob, bo, outkb);
    k_tout <<<2048, 256, 0, stream>>>(outkb, out);
}

// Round 3
// 334.201 us; speedup vs baseline: 2.8465x; 1.0202x over previous
//
#include <hip/hip_runtime.h>
#include <math.h>

// K=30 bands, B=4, T=512, N=128, Vd=64, NKB=120
typedef __attribute__((ext_vector_type(8))) short bf16x8;
typedef __attribute__((ext_vector_type(4))) float f32x4;

#define MFMA(a, b, c) __builtin_amdgcn_mfma_f32_16x16x32_bf16((a), (b), (c), 0, 0, 0)

__device__ inline unsigned short f2b(float f) {
    unsigned u = __builtin_bit_cast(unsigned, f);
    u += 0x7FFF + ((u >> 16) & 1);
    return (unsigned short)(u >> 16);
}

// ws byte offsets
static constexpr size_t OFF_XB    = 0;           // bf16 120*512*128
static constexpr size_t OFF_Q     = 15728640;    // bf16 120*512*128
static constexpr size_t OFF_K     = 31457280;    // bf16 120*512*128
static constexpr size_t OFF_VT    = 47185920;    // bf16 120*64*512
static constexpr size_t OFF_OM    = 55050240;    // bf16 120*512*64
static constexpr size_t OFF_WQ    = 62914560;    // bf16 30*128*128
static constexpr size_t OFF_WK    = 63897600;    // bf16 30*128*128
static constexpr size_t OFF_WV    = 64880640;    // bf16 30*64*128
static constexpr size_t OFF_WO    = 65372160;    // bf16 30*128*64
static constexpr size_t OFF_RS    = 65863680;    // f32 120*512*8
static constexpr size_t OFF_LAM   = 67829760;    // f32 120
static constexpr size_t OFF_OUTKB = 67830272;    // f32 120*512*128

__global__ __launch_bounds__(256) void k_tin(const float* __restrict__ x, unsigned short* __restrict__ xb) {
    int b = blockIdx.x >> 9, t = blockIdx.x & 511;
    __shared__ float ld[3840];
    const float* xp = x + ((size_t)b * 1966080 + (size_t)t * 30);
    for (int idx = threadIdx.x; idx < 3840; idx += 256) {
        int n = idx / 30, k = idx - n * 30;
        ld[idx] = xp[(size_t)n * 15360 + k];
    }
    __syncthreads();
    for (int idx = threadIdx.x; idx < 3840; idx += 256) {
        int k = idx >> 7, n = idx & 127;
        xb[(((size_t)(k * 4 + b)) * 512 + t) * 128 + n] = f2b(ld[n * 30 + k]);
    }
}

__global__ __launch_bounds__(256) void k_wcast(const float* __restrict__ Wq, const float* __restrict__ Wk,
        const float* __restrict__ Wv, const float* __restrict__ Wo,
        unsigned short* __restrict__ wq, unsigned short* __restrict__ wk,
        unsigned short* __restrict__ wv, unsigned short* __restrict__ wo) {
    int idx = blockIdx.x * 256 + threadIdx.x;
    if (idx < 491520)       wq[idx] = f2b(Wq[idx]);
    else if (idx < 983040)  wk[idx - 491520] = f2b(Wk[idx - 491520]);
    else if (idx < 1228800) wv[idx - 983040] = f2b(Wv[idx - 983040]);
    else if (idx < 1474560) wo[idx - 1228800] = f2b(Wo[idx - 1228800]);
}

// grid (kb=120, tile=8): same-kb blocks -> same XCD (120 % 8 == 0)
__global__ __launch_bounds__(256) void k_qkv(const unsigned short* __restrict__ xb,
        const unsigned short* __restrict__ wq, const unsigned short* __restrict__ wk,
        const unsigned short* __restrict__ wv,
        unsigned short* __restrict__ qb, unsigned short* __restrict__ kb_, unsigned short* __restrict__ vT) {
    int kb = blockIdx.x, band = kb >> 2;
    int tid = threadIdx.x, lane = tid & 63;
    int t0 = blockIdx.y * 64 + (tid >> 6) * 16;
    int rA = lane & 15, kq = (lane >> 4) * 8;
    const unsigned short* ap = xb + ((size_t)kb * 512 + t0 + rA) * 128 + kq;
    bf16x8 a0 = *(const bf16x8*)(ap);
    bf16x8 a1 = *(const bf16x8*)(ap + 32);
    bf16x8 a2 = *(const bf16x8*)(ap + 64);
    bf16x8 a3 = *(const bf16x8*)(ap + 96);
    f32x4 zero = {};
    for (int sel = 0; sel < 2; ++sel) {
        const unsigned short* W = (sel ? wk : wq) + (size_t)band * 16384;
        unsigned short* O = (sel ? kb_ : qb);
#pragma unroll
        for (int mt = 0; mt < 8; ++mt) {
            int m0 = mt * 16;
            const unsigned short* bp = W + (size_t)(m0 + rA) * 128 + kq;
            bf16x8 b0 = *(const bf16x8*)(bp);
            bf16x8 b1 = *(const bf16x8*)(bp + 32);
            bf16x8 b2 = *(const bf16x8*)(bp + 64);
            bf16x8 b3 = *(const bf16x8*)(bp + 96);
            f32x4 c = zero;
            c = MFMA(a0, b0, c); c = MFMA(a1, b1, c); c = MFMA(a2, b2, c); c = MFMA(a3, b3, c);
#pragma unroll
            for (int r = 0; r < 4; ++r) {
                int t = t0 + (lane >> 4) * 4 + r;
                O[((size_t)kb * 512 + t) * 128 + m0 + rA] = f2b(c[r]);
            }
        }
    }
#pragma unroll
    for (int mt = 0; mt < 4; ++mt) {
        int m0 = mt * 16;
        const unsigned short* bp = wv + (size_t)band * 8192 + (size_t)(m0 + rA) * 128 + kq;
        bf16x8 b0 = *(const bf16x8*)(bp);
        bf16x8 b1 = *(const bf16x8*)(bp + 32);
        bf16x8 b2 = *(const bf16x8*)(bp + 64);
        bf16x8 b3 = *(const bf16x8*)(bp + 96);
        f32x4 c = zero;
        c = MFMA(a0, b0, c); c = MFMA(a1, b1, c); c = MFMA(a2, b2, c); c = MFMA(a3, b3, c);
#pragma unroll
        for (int r = 0; r < 4; ++r) {
            int t = t0 + (lane >> 4) * 4 + r;
            vT[((size_t)kb * 64 + m0 + rA) * 512 + t] = f2b(c[r]);
        }
    }
}

// raw row stats (sum e, sum e^2, max lg, min lg) per map; reg-double-buffered K prefetch
__global__ __launch_bounds__(256) void k_stats(const unsigned short* __restrict__ qb,
        const unsigned short* __restrict__ kb_, float* __restrict__ rowst) {
    int kb = blockIdx.x;
    int tid = threadIdx.x, lane = tid & 63;
    int t0 = blockIdx.y * 64 + (tid >> 6) * 16;
    int rA = lane & 15, kq = (lane >> 4) * 8;
    const unsigned short* qp = qb + ((size_t)kb * 512 + t0 + rA) * 128 + kq;
    bf16x8 qa0 = *(const bf16x8*)(qp);
    bf16x8 qa1 = *(const bf16x8*)(qp + 32);
    bf16x8 qa2 = *(const bf16x8*)(qp + 64);
    bf16x8 qa3 = *(const bf16x8*)(qp + 96);
    f32x4 zero = {};
    float sum1[4] = {}, ssq1[4] = {}, mx1[4], mn1[4];
    float sum2[4] = {}, ssq2[4] = {}, mx2[4], mn2[4];
#pragma unroll
    for (int r = 0; r < 4; ++r) { mx1[r] = -1e30f; mn1[r] = 1e30f; mx2[r] = -1e30f; mn2[r] = 1e30f; }
    const unsigned short* kbase = kb_ + (size_t)kb * 65536;

    bf16x8 kA[8], kB[8];
    auto loadK = [&](int s0, bf16x8 (&kr)[8]) {
#pragma unroll
        for (int h = 0; h < 2; ++h) {
            const unsigned short* kp = kbase + (size_t)(s0 + h * 16 + rA) * 128 + kq;
#pragma unroll
            for (int i = 0; i < 4; ++i) kr[h * 4 + i] = *(const bf16x8*)(kp + i * 32);
        }
    };
    auto comp = [&](bf16x8 (&kr)[8]) {
#pragma unroll
        for (int h = 0; h < 2; ++h) {
            f32x4 c1 = MFMA(qa1, kr[h * 4 + 1], MFMA(qa0, kr[h * 4 + 0], zero));
            f32x4 c2 = MFMA(qa3, kr[h * 4 + 3], MFMA(qa2, kr[h * 4 + 2], zero));
#pragma unroll
            for (int r = 0; r < 4; ++r) {
                float lg = c1[r] * 0.25f;
                float e = __expf(lg);
                sum1[r] += e; ssq1[r] = fmaf(e, e, ssq1[r]);
                mx1[r] = fmaxf(mx1[r], lg); mn1[r] = fminf(mn1[r], lg);
                lg = c2[r] * 0.25f;
                e = __expf(lg);
                sum2[r] += e; ssq2[r] = fmaf(e, e, ssq2[r]);
                mx2[r] = fmaxf(mx2[r], lg); mn2[r] = fminf(mn2[r], lg);
            }
        }
    };
    loadK(0, kA);
#pragma unroll
    for (int it = 0; it < 16; ++it) {
        if ((it & 1) == 0) { if (it < 15) loadK((it + 1) * 32, kB); comp(kA); }
        else               { if (it < 15) loadK((it + 1) * 32, kA); comp(kB); }
    }
#pragma unroll
    for (int off = 1; off < 16; off <<= 1) {
#pragma unroll
        for (int r = 0; r < 4; ++r) {
            sum1[r] += __shfl_xor(sum1[r], off); ssq1[r] += __shfl_xor(ssq1[r], off);
            mx1[r] = fmaxf(mx1[r], __shfl_xor(mx1[r], off)); mn1[r] = fminf(mn1[r], __shfl_xor(mn1[r], off));
            sum2[r] += __shfl_xor(sum2[r], off); ssq2[r] += __shfl_xor(ssq2[r], off);
            mx2[r] = fmaxf(mx2[r], __shfl_xor(mx2[r], off)); mn2[r] = fminf(mn2[r], __shfl_xor(mn2[r], off));
        }
    }
    if ((lane & 15) == 0) {
#pragma unroll
        for (int r = 0; r < 4; ++r) {
            float* rp = rowst + ((size_t)kb * 512 + t0 + (lane >> 4) * 4 + r) * 8;
            rp[0] = sum1[r]; rp[1] = ssq1[r]; rp[2] = mx1[r]; rp[3] = mn1[r];
            rp[4] = sum2[r]; rp[5] = ssq2[r]; rp[6] = mx2[r]; rp[7] = mn2[r];
        }
    }
}

__global__ __launch_bounds__(256) void k_lam(const float* __restrict__ rowst,
        const float* __restrict__ W1, const float* __restrict__ b1,
        const float* __restrict__ W2, const float* __restrict__ b2, float* __restrict__ lam) {
    int kb = blockIdx.x, band = kb >> 2;
    int tid = threadIdx.x;
    float ss1 = 0.f, mx1 = -1e30f, mn1 = 1e30f, ss2 = 0.f, mx2 = -1e30f, mn2 = 1e30f;
    for (int t = tid; t < 512; t += 256) {
        const float* r = rowst + ((size_t)kb * 512 + t) * 8;
        float is1 = 1.0f / r[0], is2 = 1.0f / r[4];
        ss1 += r[1] * is1 * is1;
        mx1 = fmaxf(mx1, __expf(r[2]) * is1); mn1 = fminf(mn1, __expf(r[3]) * is1);
        ss2 += r[5] * is2 * is2;
        mx2 = fmaxf(mx2, __expf(r[6]) * is2); mn2 = fminf(mn2, __expf(r[7]) * is2);
    }
    __shared__ float red[256 * 6];
    red[tid] = ss1; red[256 + tid] = mx1; red[512 + tid] = mn1;
    red[768 + tid] = ss2; red[1024 + tid] = mx2; red[1280 + tid] = mn2;
    __syncthreads();
    for (int h = 128; h > 0; h >>= 1) {
        if (tid < h) {
            red[tid] += red[tid + h];
            red[256 + tid] = fmaxf(red[256 + tid], red[256 + tid + h]);
            red[512 + tid] = fminf(red[512 + tid], red[512 + tid + h]);
            red[768 + tid] += red[768 + tid + h];
            red[1024 + tid] = fmaxf(red[1024 + tid], red[1024 + tid + h]);
            red[1280 + tid] = fminf(red[1280 + tid], red[1280 + tid + h]);
        }
        __syncthreads();
    }
    if (tid == 0) {
        float stats[8];
        stats[0] = 1.0f / 512.0f;
        stats[1] = sqrtf(fmaxf(red[0] - 1.0f, 0.0f) / 262143.0f);
        stats[2] = red[256]; stats[3] = red[512];
        stats[4] = 1.0f / 512.0f;
        stats[5] = sqrtf(fmaxf(red[768] - 1.0f, 0.0f) / 262143.0f);
        stats[6] = red[1024]; stats[7] = red[1280];
        float z = b2[band];
        for (int hh = 0; hh < 16; ++hh) {
            float a = b1[band * 16 + hh];
            for (int i = 0; i < 8; ++i) a += stats[i] * W1[band * 128 + hh * 8 + i];
            z += fmaxf(a, 0.0f) * W2[band * 16 + hh];
        }
        lam[kb] = 1.0f / (1.0f + __expf(-z));
    }
}

// MFMA logits -> p bf16 via per-wave LDS -> PV MFMA; reg-double-buffered K/V prefetch
__global__ __launch_bounds__(256) void k_pv(const unsigned short* __restrict__ qb,
        const unsigned short* __restrict__ kb_, const unsigned short* __restrict__ vT,
        const float* __restrict__ rowst, const float* __restrict__ lamv,
        unsigned short* __restrict__ omid) {
    int kb = blockIdx.x;
    int tid = threadIdx.x, lane = tid & 63, w = tid >> 6;
    int t0 = blockIdx.y * 64 + w * 16;
    int rA = lane & 15, kq = (lane >> 4) * 8;
    __shared__ unsigned short plds[4][2][16 * 40];  // [wave][dbuf][row][40]
    const unsigned short* qp = qb + ((size_t)kb * 512 + t0 + rA) * 128 + kq;
    bf16x8 qa0 = *(const bf16x8*)(qp);
    bf16x8 qa1 = *(const bf16x8*)(qp + 32);
    bf16x8 qa2 = *(const bf16x8*)(qp + 64);
    bf16x8 qa3 = *(const bf16x8*)(qp + 96);
    float il1[4], il2[4];
#pragma unroll
    for (int r = 0; r < 4; ++r) {
        const float* rp = rowst + ((size_t)kb * 512 + t0 + (lane >> 4) * 4 + r) * 8;
        il1[r] = 1.0f / rp[0]; il2[r] = 1.0f / rp[4];
    }
    float lam = lamv[kb];
    f32x4 zero = {};
    f32x4 acc[4] = {zero, zero, zero, zero};
    const unsigned short* kbase = kb_ + (size_t)kb * 65536;
    const unsigned short* vbase = vT + (size_t)kb * 32768;

    bf16x8 kA[8], kB[8], vA[4], vB[4];
    auto loadC = [&](int s0, bf16x8 (&kr)[8], bf16x8 (&vr)[4]) {
#pragma unroll
        for (int h = 0; h < 2; ++h) {
            const unsigned short* kp = kbase + (size_t)(s0 + h * 16 + rA) * 128 + kq;
#pragma unroll
            for (int i = 0; i < 4; ++i) kr[h * 4 + i] = *(const bf16x8*)(kp + i * 32);
        }
#pragma unroll
        for (int vt = 0; vt < 4; ++vt) vr[vt] = *(const bf16x8*)(vbase + (size_t)(vt * 16 + rA) * 512 + s0 + kq);
    };
    auto comp = [&](int it, bf16x8 (&kr)[8], bf16x8 (&vr)[4]) {
        int db = it & 1;
#pragma unroll
        for (int h = 0; h < 2; ++h) {
            f32x4 c1 = MFMA(qa1, kr[h * 4 + 1], MFMA(qa0, kr[h * 4 + 0], zero));
            f32x4 c2 = MFMA(qa3, kr[h * 4 + 3], MFMA(qa2, kr[h * 4 + 2], zero));
#pragma unroll
            for (int r = 0; r < 4; ++r) {
                float e1 = __expf(c1[r] * 0.25f) * il1[r];
                float e2 = __expf(c2[r] * 0.25f) * il2[r];
                plds[w][db][((lane >> 4) * 4 + r) * 40 + h * 16 + rA] = f2b(e1 - lam * e2);
            }
        }
        bf16x8 pa = *(const bf16x8*)(&plds[w][db][rA * 40 + kq]);
#pragma unroll
        for (int vt = 0; vt < 4; ++vt) acc[vt] = MFMA(pa, vr[vt], acc[vt]);
    };
    loadC(0, kA, vA);
#pragma unroll
    for (int it = 0; it < 16; ++it) {
        if ((it & 1) == 0) { if (it < 15) loadC((it + 1) * 32, kB, vB); comp(it, kA, vA); }
        else               { if (it < 15) loadC((it + 1) * 32, kA, vA); comp(it, kB, vB); }
    }
#pragma unroll
    for (int vt = 0; vt < 4; ++vt)
#pragma unroll
        for (int r = 0; r < 4; ++r) {
            int t = t0 + (lane >> 4) * 4 + r;
            omid[((size_t)kb * 512 + t) * 64 + vt * 16 + rA] = f2b(acc[vt][r]);
        }
}

__global__ __launch_bounds__(256) void k_wo(const unsigned short* __restrict__ omid,
        const unsigned short* __restrict__ wo, const float* __restrict__ bo,
        float* __restrict__ outkb) {
    int kb = blockIdx.x, band = kb >> 2;
    int tid = threadIdx.x, lane = tid & 63;
    int t0 = blockIdx.y * 64 + (tid >> 6) * 16;
    int rA = lane & 15, kq = (lane >> 4) * 8;
    const unsigned short* ap = omid + ((size_t)kb * 512 + t0 + rA) * 64 + kq;
    bf16x8 a0 = *(const bf16x8*)(ap);
    bf16x8 a1 = *(const bf16x8*)(ap + 32);
    f32x4 zero = {};
#pragma unroll
    for (int mt = 0; mt < 8; ++mt) {
        int m0 = mt * 16;
        const unsigned short* bp = wo + (size_t)band * 8192 + (size_t)(m0 + rA) * 64 + kq;
        bf16x8 b0 = *(const bf16x8*)(bp);
        bf16x8 b1 = *(const bf16x8*)(bp + 32);
        f32x4 c = MFMA(a1, b1, MFMA(a0, b0, zero));
        float bias = bo[band * 128 + m0 + rA];
#pragma unroll
        for (int r = 0; r < 4; ++r) {
            int t = t0 + (lane >> 4) * 4 + r;
            outkb[((size_t)kb * 512 + t) * 128 + m0 + rA] = c[r] + bias;
        }
    }
}

__global__ __launch_bounds__(256) void k_tout(const float* __restrict__ outkb, float* __restrict__ out) {
    int b = blockIdx.x >> 9, t = blockIdx.x & 511;
    __shared__ float ld[30 * 129];
    for (int idx = threadIdx.x; idx < 3840; idx += 256) {
        int k = idx >> 7, n = idx & 127;
        ld[k * 129 + n] = outkb[(((size_t)(k * 4 + b)) * 512 + t) * 128 + n];
    }
    __syncthreads();
    float* op = out + ((size_t)b * 1966080 + (size_t)t * 30);
    for (int idx = threadIdx.x; idx < 3840; idx += 256) {
        int n = idx / 30, k = idx - n * 30;
        op[(size_t)n * 15360 + k] = ld[k * 129 + n];
    }
}

extern "C" void kernel_launch(void* const* d_in, const int* in_sizes, int n_in,
                              void* d_out, int out_size, void* d_ws, size_t ws_size,
                              hipStream_t stream) {
    (void)in_sizes; (void)n_in; (void)out_size; (void)ws_size;
    const float* x  = (const float*)d_in[0];
    const float* Wq = (const float*)d_in[1];
    const float* Wk = (const float*)d_in[2];
    const float* Wv = (const float*)d_in[3];
    const float* Wo = (const float*)d_in[4];
    const float* bo = (const float*)d_in[5];
    const float* W1 = (const float*)d_in[6];
    const float* b1 = (const float*)d_in[7];
    const float* W2 = (const float*)d_in[8];
    const float* b2 = (const float*)d_in[9];
    float* out = (float*)d_out;
    char* ws = (char*)d_ws;

    unsigned short* xb  = (unsigned short*)(ws + OFF_XB);
    unsigned short* qb  = (unsigned short*)(ws + OFF_Q);
    unsigned short* kbb = (unsigned short*)(ws + OFF_K);
    unsigned short* vT  = (unsigned short*)(ws + OFF_VT);
    unsigned short* om  = (unsigned short*)(ws + OFF_OM);
    unsigned short* wqb = (unsigned short*)(ws + OFF_WQ);
    unsigned short* wkb = (unsigned short*)(ws + OFF_WK);
    unsigned short* wvb = (unsigned short*)(ws + OFF_WV);
    unsigned short* wob = (unsigned short*)(ws + OFF_WO);
    float* rowst = (float*)(ws + OFF_RS);
    float* lam   = (float*)(ws + OFF_LAM);
    float* outkb = (float*)(ws + OFF_OUTKB);

    k_tin  <<<2048, 256, 0, stream>>>(x, xb);
    k_wcast<<<5760, 256, 0, stream>>>(Wq, Wk, Wv, Wo, wqb, wkb, wvb, wob);
    k_qkv  <<<dim3(120, 8), 256, 0, stream>>>(xb, wqb, wkb, wvb, qb, kbb, vT);
    k_stats<<<dim3(120, 8), 256, 0, stream>>>(qb, kbb, rowst);
    k_lam  <<<120, 256, 0, stream>>>(rowst, W1, b1, W2, b2, lam);
    k_pv   <<<dim3(120, 8), 256, 0, stream>>>(qb, kbb, vT, rowst, lam, om);
    k_wo   <<<dim3(120, 8), 256, 0, stream>>>(om, wob, bo, outkb);
    k_tout <<<2048, 256, 0, stream>>>(outkb, out);
}